// Round 9
// baseline (286.226 us; speedup 1.0000x reference)
//
#include <hip/hip_runtime.h>

#define AS1 __attribute__((address_space(1)))
#define AS3 __attribute__((address_space(3)))

typedef __attribute__((ext_vector_type(8))) short bf16x8;
typedef __attribute__((ext_vector_type(4))) float f32x4;

#define N_TOK 8192
#define CD 1024
#define ID 1024
#define BM 128
#define BN 128
#define BK 64
#define MAXMT 72   // 8*9; XCD-chunk remap (x&7)*9 + (x>>3) is bijective

// ---- workspace layout (bytes) ----
#define XB_OFF   0LL            // x bf16 [N,C]                16MB
#define W1B_OFF  16777216LL     // W1^T bf16 [E][I][C]         16MB
#define WGB_OFF  33554432LL     // Wg^T bf16 [E][I][C]         16MB
#define W2B_OFF  50331648LL     // W2^T bf16 [E][C][I]         16MB
#define ACT_OFF  67108864LL     // act bf16 [2N][I]            32MB
#define ST_OFF   100663296LL    // slot_token int [2N]
#define SW_OFF   100728832LL    // slot_w float [2N]
#define TE_OFF   100794368LL    // tok_e int [N*2]
#define TW_OFF   100859904LL    // tok_w float [N*2]
#define META_OFF 100925440LL    // counts[16] offs[16] (pad) TO[2][9]

static __device__ __forceinline__ unsigned short f2bf(float f) {
  union { float f; unsigned u; } v; v.f = f;
  unsigned r = v.u + 0x7fffu + ((v.u >> 16) & 1u);
  return (unsigned short)(r >> 16);
}

// ============ router + x->bf16: 4 tokens/block (r7 proven config) ============
__global__ __launch_bounds__(256) void moe_router_cvt(
    const float* __restrict__ x, const float* __restrict__ Wr,
    const float* __restrict__ br, unsigned short* __restrict__ xb,
    int* __restrict__ tok_e, float* __restrict__ tok_w) {
  const int tid = threadIdx.x;
  __shared__ float wr_s[256 * 33];
  __shared__ float red[8 * 256];
  __shared__ float lg_s[8];

#pragma unroll
  for (int k = 0; k < 8; k++) {
    const float4 w = *(const float4*)(Wr + (long)(k * 256 + tid) * 4);
    const int row = k * 32 + (tid >> 3);
    const int col = (tid * 4) & 31;
    float* d = wr_s + row * 33 + col;
    d[0] = w.x; d[1] = w.y; d[2] = w.z; d[3] = w.w;
  }
  __syncthreads();

  const int c0 = tid * 4;
  const float* wrow = wr_s + tid * 33;
#pragma unroll 1
  for (int it = 0; it < 4; it++) {
    const int t = blockIdx.x * 4 + it;
    const long xoff = (long)t * CD + c0;
    const float4 xv = *(const float4*)(x + xoff);
    uint2 ob;
    ob.x = (unsigned)f2bf(xv.x) | ((unsigned)f2bf(xv.y) << 16);
    ob.y = (unsigned)f2bf(xv.z) | ((unsigned)f2bf(xv.w) << 16);
    *(uint2*)(xb + xoff) = ob;

    const float xj[4] = {xv.x, xv.y, xv.z, xv.w};
    float acc[8];
#pragma unroll
    for (int e = 0; e < 8; e++) acc[e] = 0.f;
#pragma unroll
    for (int j = 0; j < 4; j++)
#pragma unroll
      for (int e = 0; e < 8; e++)
        acc[e] += xj[j] * wrow[j * 8 + e];
#pragma unroll
    for (int e = 0; e < 8; e++) red[e * 256 + tid] = acc[e];
    __syncthreads();
    {
      const int e = tid >> 5, l = tid & 31;
      float s = 0.f;
#pragma unroll
      for (int k = 0; k < 8; k++) s += red[e * 256 + l + k * 32];
#pragma unroll
      for (int off = 16; off; off >>= 1) s += __shfl_xor(s, off);
      if (l == 0) lg_s[e] = s;
    }
    __syncthreads();
    if (tid == 0) {
      float lg[8];
#pragma unroll
      for (int e = 0; e < 8; e++) lg[e] = lg_s[e] + br[e];
      int i1 = 0; float m1v = lg[0];
#pragma unroll
      for (int e = 1; e < 8; e++) if (lg[e] > m1v) { m1v = lg[e]; i1 = e; }
      int i2 = -1; float m2v = -1e30f;
#pragma unroll
      for (int e = 0; e < 8; e++) if (e != i1 && lg[e] > m2v) { m2v = lg[e]; i2 = e; }
      float s = 0.f;
#pragma unroll
      for (int e = 0; e < 8; e++) s += __expf(lg[e] - m1v);
      const float w1v = 1.f / s;
      const float w2v = __expf(m2v - m1v) / s;
      tok_e[2 * t] = i1; tok_e[2 * t + 1] = i2;
      tok_w[2 * t] = w1v; tok_w[2 * t + 1] = w2v;
    }
    __syncthreads();
  }
}

// ============ sort: counts/offsets/stable scatter, zero atomics ============
__global__ __launch_bounds__(256) void moe_sort(
    const int* __restrict__ tok_e, const float* __restrict__ tok_w,
    int* __restrict__ meta, int* __restrict__ slot_token,
    float* __restrict__ slot_w) {
  const int tid = threadIdx.x;
  __shared__ int cnt[16 * 256];
  __shared__ int base[16 * 256];
  __shared__ int offs_s[16];

#pragma unroll
  for (int c = 0; c < 16; c++) cnt[c * 256 + tid] = 0;
  __syncthreads();
  const int t0 = tid * 32;
#pragma unroll 4
  for (int i = 0; i < 32; i++) {
    const int t = t0 + i;
    cnt[tok_e[2 * t] * 256 + tid]++;
    cnt[(8 + tok_e[2 * t + 1]) * 256 + tid]++;
  }
  __syncthreads();
  {
    const int w = tid >> 6, lane = tid & 63;
#pragma unroll
    for (int q = 0; q < 4; q++) {
      const int c = w * 4 + q;
      int carry = 0;
#pragma unroll
      for (int ch = 0; ch < 4; ch++) {
        const int v = cnt[c * 256 + ch * 64 + lane];
        int incl = v;
#pragma unroll
        for (int off = 1; off < 64; off <<= 1) {
          const int u = __shfl_up(incl, off);
          if (lane >= off) incl += u;
        }
        base[c * 256 + ch * 64 + lane] = incl - v + carry;
        carry += __shfl(incl, 63);
      }
      if (lane == 0) meta[c] = carry;
    }
  }
  __syncthreads();
  if (tid == 0) {
    int* counts = meta; int* offs = meta + 16; int* TO = meta + 48;
    for (int k = 0; k < 2; k++) {
      int o = 0, tl = 0;
      TO[k * 9] = 0;
      for (int e = 0; e < 8; e++) {
        offs[k * 8 + e] = o;
        offs_s[k * 8 + e] = o;
        o += counts[k * 8 + e];
        tl += (counts[k * 8 + e] + BM - 1) / BM;
        TO[k * 9 + e + 1] = tl;
      }
    }
  }
  __syncthreads();
#pragma unroll
  for (int c = 0; c < 16; c++) cnt[c * 256 + tid] = 0;
  __syncthreads();
#pragma unroll 4
  for (int i = 0; i < 32; i++) {
    const int t = t0 + i;
#pragma unroll
    for (int k = 0; k < 2; k++) {
      const int e = tok_e[2 * t + k];
      const int idx = k * 8 + e;
      const int r = cnt[idx * 256 + tid]++;
      const int slot = offs_s[idx] + base[idx * 256 + tid] + r;
      slot_token[k * N_TOK + slot] = t;
      slot_w[k * N_TOK + slot] = tok_w[2 * t + k];
    }
  }
}

// ---------------- weight transpose + fp32->bf16 (24 x 1024x1024) ----------------
__global__ __launch_bounds__(256) void moe_tw(const float* __restrict__ W1,
                                              const float* __restrict__ Wg,
                                              const float* __restrict__ W2,
                                              unsigned short* __restrict__ w1b,
                                              unsigned short* __restrict__ wgb,
                                              unsigned short* __restrict__ w2b) {
  const int z = blockIdx.z;
  const float* src; unsigned short* dst;
  if (z < 8)       { src = W1 + (long)z * 1048576;        dst = w1b + (long)z * 1048576; }
  else if (z < 16) { src = Wg + (long)(z - 8) * 1048576;  dst = wgb + (long)(z - 8) * 1048576; }
  else             { src = W2 + (long)(z - 16) * 1048576; dst = w2b + (long)(z - 16) * 1048576; }
  __shared__ float tbuf[64][65];
  const int tx = threadIdx.x & 63, ty = threadIdx.x >> 6;
  const int r0 = blockIdx.y * 64, c0 = blockIdx.x * 64;
#pragma unroll
  for (int j = 0; j < 64; j += 4)
    tbuf[ty + j][tx] = src[(long)(r0 + ty + j) * 1024 + c0 + tx];
  __syncthreads();
#pragma unroll
  for (int j = 0; j < 64; j += 4)
    dst[(long)(c0 + ty + j) * 1024 + r0 + tx] = f2bf(tbuf[tx][ty + j]);
}

// ---------------- phase 1: act = silu(x W1 + b1) * (x Wg + bg) ----------------
__global__ __launch_bounds__(256, 2) void moe_phase1(
    const unsigned short* __restrict__ xb, const unsigned short* __restrict__ w1b,
    const unsigned short* __restrict__ wgb, const float* __restrict__ b1,
    const float* __restrict__ bg, unsigned short* __restrict__ act,
    const int* __restrict__ slot_token, const int* __restrict__ meta) {
  const int kpl = blockIdx.z;
  const int* counts = meta;
  const int* offs = meta + 16;
  const int* TO = meta + 48 + kpl * 9;
  const int bx = blockIdx.x;
  const int mt = (bx & 7) * 9 + (bx >> 3);   // T1 XCD-chunk remap
  if (mt >= TO[8]) return;
  int e = 0;
#pragma unroll
  for (int q = 1; q < 8; q++) if (mt >= TO[q]) e = q;
  const int seg_start = offs[kpl * 8 + e];
  const int seg_n = counts[kpl * 8 + e];
  const int m0 = seg_start + (mt - TO[e]) * BM;
  const int rows_valid = min(BM, seg_start + seg_n - m0);
  const int nb = blockIdx.y * BN;
  const int tid = threadIdx.x, wid = tid >> 6, lane = tid & 63;
  const int wm = wid >> 1, wn = wid & 1;
  const int lane15 = lane & 15, lq = lane >> 4;

  __shared__ __align__(16) char lds[49152];  // A:0  B1:16K  Bg:32K

  const int l8 = lane >> 3, ch = lane & 7;
  long a_byte[4], b_byte[4];
#pragma unroll
  for (int i = 0; i < 4; i++) {
    const int r = wid * 32 + i * 8 + l8;
    const int rr = min(r, rows_valid - 1);
    const int tok = slot_token[kpl * N_TOK + m0 + rr];
    const int chs = ch ^ (r & 7);
    a_byte[i] = ((long)tok * CD + chs * 8) * 2;
    b_byte[i] = ((long)(e * ID + nb + r) * CD + chs * 8) * 2;
  }
  f32x4 acc_h[4][4], acc_g[4][4];
#pragma unroll
  for (int mi = 0; mi < 4; mi++)
#pragma unroll
    for (int ni = 0; ni < 4; ni++) { acc_h[mi][ni] = 0.f; acc_g[mi][ni] = 0.f; }

  for (int kb = 0; kb < CD; kb += BK) {
#pragma unroll
    for (int i = 0; i < 4; i++) {
      __builtin_amdgcn_global_load_lds(
          (const AS1 void*)((const char*)xb + a_byte[i]),
          (AS3 void*)(lds + (wid * 32 + i * 8) * 128), 16, 0, 0);
      a_byte[i] += 128;
    }
#pragma unroll
    for (int i = 0; i < 4; i++) {
      __builtin_amdgcn_global_load_lds(
          (const AS1 void*)((const char*)w1b + b_byte[i]),
          (AS3 void*)(lds + 16384 + (wid * 32 + i * 8) * 128), 16, 0, 0);
      __builtin_amdgcn_global_load_lds(
          (const AS1 void*)((const char*)wgb + b_byte[i]),
          (AS3 void*)(lds + 32768 + (wid * 32 + i * 8) * 128), 16, 0, 0);
      b_byte[i] += 128;
    }
    __syncthreads();
#pragma unroll
    for (int ks = 0; ks < 2; ks++) {
      bf16x8 af[4], bf1[4], bfg[4];
#pragma unroll
      for (int mi = 0; mi < 4; mi++) {
        const int row = wm * 64 + mi * 16 + lane15;
        const int byt = row * 128 + ((ks * 64 + lq * 16) ^ ((row & 7) << 4));
        af[mi] = *(const bf16x8*)(lds + byt);
      }
#pragma unroll
      for (int ni = 0; ni < 4; ni++) {
        const int row = wn * 64 + ni * 16 + lane15;
        const int byt = row * 128 + ((ks * 64 + lq * 16) ^ ((row & 7) << 4));
        bf1[ni] = *(const bf16x8*)(lds + 16384 + byt);
        bfg[ni] = *(const bf16x8*)(lds + 32768 + byt);
      }
#pragma unroll
      for (int mi = 0; mi < 4; mi++)
#pragma unroll
        for (int ni = 0; ni < 4; ni++) {
          acc_h[mi][ni] = __builtin_amdgcn_mfma_f32_16x16x32_bf16(af[mi], bf1[ni], acc_h[mi][ni], 0, 0, 0);
          acc_g[mi][ni] = __builtin_amdgcn_mfma_f32_16x16x32_bf16(af[mi], bfg[ni], acc_g[mi][ni], 0, 0, 0);
        }
    }
    __syncthreads();
  }

  // epilogue: silu(h)*g -> bf16, repack through LDS for coalesced store
  unsigned short* rp = (unsigned short*)lds;
#pragma unroll
  for (int mi = 0; mi < 4; mi++) {
#pragma unroll
    for (int ni = 0; ni < 4; ni++) {
      const int colLoc = wn * 64 + ni * 16 + lane15;
      const float bb1 = b1[e * ID + nb + colLoc];
      const float bbg = bg[e * ID + nb + colLoc];
#pragma unroll
      for (int j = 0; j < 4; j++) {
        const int row = wm * 64 + mi * 16 + lq * 4 + j;
        const float h = acc_h[mi][ni][j] + bb1;
        const float g = acc_g[mi][ni][j] + bbg;
        const float sv = h / (1.f + __expf(-h));
        rp[row * 128 + colLoc] = f2bf(sv * g);
      }
    }
  }
  __syncthreads();
  const long base = ((long)(kpl * N_TOK + m0)) * ID + nb;
#pragma unroll
  for (int it = 0; it < 8; it++) {
    const int chunk = it * 256 + tid;
    const int row = chunk >> 4;
    const int cc = (chunk & 15) * 8;
    if (row < rows_valid)
      *(uint4*)(act + base + (long)row * ID + cc) = *(const uint4*)(rp + row * 128 + cc);
  }
}

// ------- phase 2: dual-N (2 MFMAs per staged A-byte) + merged planes -------
// Grid (72,4,2) = 576 blocks (>= 2/CU: r8 lesson — this structure needs a
// co-resident partner block). out pre-zeroed; exactly 2 atomic contributions
// per element (k=0,k=1) from distinct blocks; float add of 2 operands is
// commutative -> bit-deterministic; distinct addresses -> no serialization.
__global__ __launch_bounds__(256, 2) void moe_phase2(
    const unsigned short* __restrict__ act, const unsigned short* __restrict__ w2b,
    const float* __restrict__ b2, const int* __restrict__ slot_token,
    const float* __restrict__ slot_w, float* __restrict__ out,
    const int* __restrict__ meta) {
  const int kpl = blockIdx.z;
  const int* counts = meta;
  const int* offs = meta + 16;
  const int* TO = meta + 48 + kpl * 9;
  const int bx = blockIdx.x;
  const int mt = (bx & 7) * 9 + (bx >> 3);   // T1 XCD-chunk remap
  if (mt >= TO[8]) return;
  int e = 0;
#pragma unroll
  for (int q = 1; q < 8; q++) if (mt >= TO[q]) e = q;
  const int seg_start = offs[kpl * 8 + e];
  const int seg_n = counts[kpl * 8 + e];
  const int m0 = seg_start + (mt - TO[e]) * BM;
  const int rows_valid = min(BM, seg_start + seg_n - m0);
  const int nb = blockIdx.y * 256;           // dual-N: 256 output cols/block
  const int tid = threadIdx.x, wid = tid >> 6, lane = tid & 63;
  const int wm = wid >> 1, wn = wid & 1;
  const int lane15 = lane & 15, lq = lane >> 4;

  __shared__ __align__(16) char lds[49152];  // A:0  B0:16K  B1:32K

  const int l8 = lane >> 3, ch = lane & 7;
  long a_byte[4], b_byte[4];
#pragma unroll
  for (int i = 0; i < 4; i++) {
    const int r = wid * 32 + i * 8 + l8;
    const int rr = min(r, rows_valid - 1);
    const int chs = ch ^ (r & 7);
    a_byte[i] = ((long)(kpl * N_TOK + m0 + rr) * ID + chs * 8) * 2;
    b_byte[i] = ((long)(e * CD + nb + r) * ID + chs * 8) * 2;
  }
  f32x4 acc_h[4][4], acc_g[4][4];   // h: cols nb.., g: cols nb+128..
#pragma unroll
  for (int mi = 0; mi < 4; mi++)
#pragma unroll
    for (int ni = 0; ni < 4; ni++) { acc_h[mi][ni] = 0.f; acc_g[mi][ni] = 0.f; }

  for (int kb = 0; kb < ID; kb += BK) {
#pragma unroll
    for (int i = 0; i < 4; i++) {
      __builtin_amdgcn_global_load_lds(
          (const AS1 void*)((const char*)act + a_byte[i]),
          (AS3 void*)(lds + (wid * 32 + i * 8) * 128), 16, 0, 0);
      a_byte[i] += 128;
    }
#pragma unroll
    for (int i = 0; i < 4; i++) {
      __builtin_amdgcn_global_load_lds(
          (const AS1 void*)((const char*)w2b + b_byte[i]),
          (AS3 void*)(lds + 16384 + (wid * 32 + i * 8) * 128), 16, 0, 0);
      __builtin_amdgcn_global_load_lds(
          (const AS1 void*)((const char*)w2b + b_byte[i] + 262144LL),  // +128 rows
          (AS3 void*)(lds + 32768 + (wid * 32 + i * 8) * 128), 16, 0, 0);
      b_byte[i] += 128;
    }
    __syncthreads();
#pragma unroll
    for (int ks = 0; ks < 2; ks++) {
      bf16x8 af[4], bf0[4], bf1[4];
#pragma unroll
      for (int mi = 0; mi < 4; mi++) {
        const int row = wm * 64 + mi * 16 + lane15;
        const int byt = row * 128 + ((ks * 64 + lq * 16) ^ ((row & 7) << 4));
        af[mi] = *(const bf16x8*)(lds + byt);
      }
#pragma unroll
      for (int ni = 0; ni < 4; ni++) {
        const int row = wn * 64 + ni * 16 + lane15;
        const int byt = row * 128 + ((ks * 64 + lq * 16) ^ ((row & 7) << 4));
        bf0[ni] = *(const bf16x8*)(lds + 16384 + byt);
        bf1[ni] = *(const bf16x8*)(lds + 32768 + byt);
      }
#pragma unroll
      for (int mi = 0; mi < 4; mi++)
#pragma unroll
        for (int ni = 0; ni < 4; ni++) {
          acc_h[mi][ni] = __builtin_amdgcn_mfma_f32_16x16x32_bf16(af[mi], bf0[ni], acc_h[mi][ni], 0, 0, 0);
          acc_g[mi][ni] = __builtin_amdgcn_mfma_f32_16x16x32_bf16(af[mi], bf1[ni], acc_g[mi][ni], 0, 0, 0);
        }
    }
    __syncthreads();
  }

#pragma unroll
  for (int mi = 0; mi < 4; mi++) {
    int t4[4]; float w4[4]; int rv[4];
#pragma unroll
    for (int j = 0; j < 4; j++) {
      const int r = wm * 64 + mi * 16 + lq * 4 + j;
      rv[j] = (r < rows_valid);
      const int p = kpl * N_TOK + m0 + min(r, rows_valid - 1);
      t4[j] = slot_token[p];
      w4[j] = slot_w[p];
    }
#pragma unroll
    for (int half = 0; half < 2; half++) {
#pragma unroll
      for (int ni = 0; ni < 4; ni++) {
        const int col = nb + half * 128 + wn * 64 + ni * 16 + lane15;
        const float bb = b2[e * CD + col];
#pragma unroll
        for (int j = 0; j < 4; j++) {
          if (rv[j]) {
            const long o = (long)t4[j] * CD + col;
            const float a = half ? acc_g[mi][ni][j] : acc_h[mi][ni][j];
            atomicAdd(&out[o], (a + bb) * w4[j]);
          }
        }
      }
    }
  }
}

extern "C" void kernel_launch(void* const* d_in, const int* in_sizes, int n_in,
                              void* d_out, int out_size, void* d_ws, size_t ws_size,
                              hipStream_t stream) {
  const float* x  = (const float*)d_in[0];
  const float* Wr = (const float*)d_in[1];
  const float* br = (const float*)d_in[2];
  const float* W1 = (const float*)d_in[3];
  const float* b1 = (const float*)d_in[4];
  const float* Wg = (const float*)d_in[5];
  const float* bg = (const float*)d_in[6];
  const float* W2 = (const float*)d_in[7];
  const float* b2 = (const float*)d_in[8];
  float* out = (float*)d_out;
  char* ws = (char*)d_ws;

  unsigned short* xb  = (unsigned short*)(ws + XB_OFF);
  unsigned short* w1b = (unsigned short*)(ws + W1B_OFF);
  unsigned short* wgb = (unsigned short*)(ws + WGB_OFF);
  unsigned short* w2b = (unsigned short*)(ws + W2B_OFF);
  unsigned short* act = (unsigned short*)(ws + ACT_OFF);
  int*   slot_token = (int*)(ws + ST_OFF);
  float* slot_w     = (float*)(ws + SW_OFF);
  int*   tok_e      = (int*)(ws + TE_OFF);
  float* tok_w      = (float*)(ws + TW_OFF);
  int*   meta       = (int*)(ws + META_OFF);

  hipMemsetAsync(out, 0, (size_t)out_size * 4, stream);
  moe_router_cvt<<<N_TOK / 4, 256, 0, stream>>>(x, Wr, br, xb, tok_e, tok_w);
  moe_sort<<<1, 256, 0, stream>>>(tok_e, tok_w, meta, slot_token, slot_w);
  moe_tw<<<dim3(16, 16, 24), 256, 0, stream>>>(W1, Wg, W2, w1b, wgb, w2b);
  moe_phase1<<<dim3(MAXMT, ID / BN, 2), 256, 0, stream>>>(xb, w1b, wgb, b1, bg, act, slot_token, meta);
  moe_phase2<<<dim3(MAXMT, CD / 256, 2), 256, 0, stream>>>(act, w2b, b2, slot_token, slot_w, out, meta);
}

// Round 10
// 247.438 us; speedup vs baseline: 1.1568x; 1.1568x over previous
//
#include <hip/hip_runtime.h>

#define AS1 __attribute__((address_space(1)))
#define AS3 __attribute__((address_space(3)))

typedef __attribute__((ext_vector_type(8))) short bf16x8;
typedef __attribute__((ext_vector_type(4))) float f32x4;

#define N_TOK 8192
#define CD 1024
#define ID 1024
#define BM 128
#define BN 128
#define BK 64
#define MAXMT 72   // 8*9; XCD-chunk remap (x&7)*9 + (x>>3) is bijective

// ---- workspace layout (bytes) ----
#define XB_OFF   0LL            // x bf16 [N,C] 16MB; REUSED (with W1B) as p1 float[N][C] after phase1
#define W1B_OFF  16777216LL     // W1^T bf16 [E][I][C]         16MB
#define WGB_OFF  33554432LL     // Wg^T bf16 [E][I][C]         16MB
#define W2B_OFF  50331648LL     // W2^T bf16 [E][C][I]         16MB
#define ACT_OFF  67108864LL     // act bf16 [2N][I]            32MB
#define ST_OFF   100663296LL    // slot_token int [2N]
#define SW_OFF   100728832LL    // slot_w float [2N]
#define TE_OFF   100794368LL    // tok_e int [N*2]
#define TW_OFF   100859904LL    // tok_w float [N*2]
#define META_OFF 100925440LL    // counts[16] offs[16] (pad) TO[2][9]

static __device__ __forceinline__ unsigned short f2bf(float f) {
  union { float f; unsigned u; } v; v.f = f;
  unsigned r = v.u + 0x7fffu + ((v.u >> 16) & 1u);
  return (unsigned short)(r >> 16);
}

// ============ router + x->bf16: 4 tokens/block (r7 proven config) ============
__global__ __launch_bounds__(256) void moe_router_cvt(
    const float* __restrict__ x, const float* __restrict__ Wr,
    const float* __restrict__ br, unsigned short* __restrict__ xb,
    int* __restrict__ tok_e, float* __restrict__ tok_w) {
  const int tid = threadIdx.x;
  __shared__ float wr_s[256 * 33];
  __shared__ float red[8 * 256];
  __shared__ float lg_s[8];

#pragma unroll
  for (int k = 0; k < 8; k++) {
    const float4 w = *(const float4*)(Wr + (long)(k * 256 + tid) * 4);
    const int row = k * 32 + (tid >> 3);
    const int col = (tid * 4) & 31;
    float* d = wr_s + row * 33 + col;
    d[0] = w.x; d[1] = w.y; d[2] = w.z; d[3] = w.w;
  }
  __syncthreads();

  const int c0 = tid * 4;
  const float* wrow = wr_s + tid * 33;
#pragma unroll 1
  for (int it = 0; it < 4; it++) {
    const int t = blockIdx.x * 4 + it;
    const long xoff = (long)t * CD + c0;
    const float4 xv = *(const float4*)(x + xoff);
    uint2 ob;
    ob.x = (unsigned)f2bf(xv.x) | ((unsigned)f2bf(xv.y) << 16);
    ob.y = (unsigned)f2bf(xv.z) | ((unsigned)f2bf(xv.w) << 16);
    *(uint2*)(xb + xoff) = ob;

    const float xj[4] = {xv.x, xv.y, xv.z, xv.w};
    float acc[8];
#pragma unroll
    for (int e = 0; e < 8; e++) acc[e] = 0.f;
#pragma unroll
    for (int j = 0; j < 4; j++)
#pragma unroll
      for (int e = 0; e < 8; e++)
        acc[e] += xj[j] * wrow[j * 8 + e];
#pragma unroll
    for (int e = 0; e < 8; e++) red[e * 256 + tid] = acc[e];
    __syncthreads();
    {
      const int e = tid >> 5, l = tid & 31;
      float s = 0.f;
#pragma unroll
      for (int k = 0; k < 8; k++) s += red[e * 256 + l + k * 32];
#pragma unroll
      for (int off = 16; off; off >>= 1) s += __shfl_xor(s, off);
      if (l == 0) lg_s[e] = s;
    }
    __syncthreads();
    if (tid == 0) {
      float lg[8];
#pragma unroll
      for (int e = 0; e < 8; e++) lg[e] = lg_s[e] + br[e];
      int i1 = 0; float m1v = lg[0];
#pragma unroll
      for (int e = 1; e < 8; e++) if (lg[e] > m1v) { m1v = lg[e]; i1 = e; }
      int i2 = -1; float m2v = -1e30f;
#pragma unroll
      for (int e = 0; e < 8; e++) if (e != i1 && lg[e] > m2v) { m2v = lg[e]; i2 = e; }
      float s = 0.f;
#pragma unroll
      for (int e = 0; e < 8; e++) s += __expf(lg[e] - m1v);
      const float w1v = 1.f / s;
      const float w2v = __expf(m2v - m1v) / s;
      tok_e[2 * t] = i1; tok_e[2 * t + 1] = i2;
      tok_w[2 * t] = w1v; tok_w[2 * t + 1] = w2v;
    }
    __syncthreads();
  }
}

// ============ sort: counts/offsets/stable scatter, zero atomics ============
__global__ __launch_bounds__(256) void moe_sort(
    const int* __restrict__ tok_e, const float* __restrict__ tok_w,
    int* __restrict__ meta, int* __restrict__ slot_token,
    float* __restrict__ slot_w) {
  const int tid = threadIdx.x;
  __shared__ int cnt[16 * 256];
  __shared__ int base[16 * 256];
  __shared__ int offs_s[16];

#pragma unroll
  for (int c = 0; c < 16; c++) cnt[c * 256 + tid] = 0;
  __syncthreads();
  const int t0 = tid * 32;
#pragma unroll 4
  for (int i = 0; i < 32; i++) {
    const int t = t0 + i;
    cnt[tok_e[2 * t] * 256 + tid]++;
    cnt[(8 + tok_e[2 * t + 1]) * 256 + tid]++;
  }
  __syncthreads();
  {
    const int w = tid >> 6, lane = tid & 63;
#pragma unroll
    for (int q = 0; q < 4; q++) {
      const int c = w * 4 + q;
      int carry = 0;
#pragma unroll
      for (int ch = 0; ch < 4; ch++) {
        const int v = cnt[c * 256 + ch * 64 + lane];
        int incl = v;
#pragma unroll
        for (int off = 1; off < 64; off <<= 1) {
          const int u = __shfl_up(incl, off);
          if (lane >= off) incl += u;
        }
        base[c * 256 + ch * 64 + lane] = incl - v + carry;
        carry += __shfl(incl, 63);
      }
      if (lane == 0) meta[c] = carry;
    }
  }
  __syncthreads();
  if (tid == 0) {
    int* counts = meta; int* offs = meta + 16; int* TO = meta + 48;
    for (int k = 0; k < 2; k++) {
      int o = 0, tl = 0;
      TO[k * 9] = 0;
      for (int e = 0; e < 8; e++) {
        offs[k * 8 + e] = o;
        offs_s[k * 8 + e] = o;
        o += counts[k * 8 + e];
        tl += (counts[k * 8 + e] + BM - 1) / BM;
        TO[k * 9 + e + 1] = tl;
      }
    }
  }
  __syncthreads();
#pragma unroll
  for (int c = 0; c < 16; c++) cnt[c * 256 + tid] = 0;
  __syncthreads();
#pragma unroll 4
  for (int i = 0; i < 32; i++) {
    const int t = t0 + i;
#pragma unroll
    for (int k = 0; k < 2; k++) {
      const int e = tok_e[2 * t + k];
      const int idx = k * 8 + e;
      const int r = cnt[idx * 256 + tid]++;
      const int slot = offs_s[idx] + base[idx * 256 + tid] + r;
      slot_token[k * N_TOK + slot] = t;
      slot_w[k * N_TOK + slot] = tok_w[2 * t + k];
    }
  }
}

// ---------------- weight transpose + fp32->bf16 (24 x 1024x1024) ----------------
__global__ __launch_bounds__(256) void moe_tw(const float* __restrict__ W1,
                                              const float* __restrict__ Wg,
                                              const float* __restrict__ W2,
                                              unsigned short* __restrict__ w1b,
                                              unsigned short* __restrict__ wgb,
                                              unsigned short* __restrict__ w2b) {
  const int z = blockIdx.z;
  const float* src; unsigned short* dst;
  if (z < 8)       { src = W1 + (long)z * 1048576;        dst = w1b + (long)z * 1048576; }
  else if (z < 16) { src = Wg + (long)(z - 8) * 1048576;  dst = wgb + (long)(z - 8) * 1048576; }
  else             { src = W2 + (long)(z - 16) * 1048576; dst = w2b + (long)(z - 16) * 1048576; }
  __shared__ float tbuf[64][65];
  const int tx = threadIdx.x & 63, ty = threadIdx.x >> 6;
  const int r0 = blockIdx.y * 64, c0 = blockIdx.x * 64;
#pragma unroll
  for (int j = 0; j < 64; j += 4)
    tbuf[ty + j][tx] = src[(long)(r0 + ty + j) * 1024 + c0 + tx];
  __syncthreads();
#pragma unroll
  for (int j = 0; j < 64; j += 4)
    dst[(long)(c0 + ty + j) * 1024 + r0 + tx] = f2bf(tbuf[tx][ty + j]);
}

// ---------------- phase 1: act = silu(x W1 + b1) * (x Wg + bg) ----------------
__global__ __launch_bounds__(256, 2) void moe_phase1(
    const unsigned short* __restrict__ xb, const unsigned short* __restrict__ w1b,
    const unsigned short* __restrict__ wgb, const float* __restrict__ b1,
    const float* __restrict__ bg, unsigned short* __restrict__ act,
    const int* __restrict__ slot_token, const int* __restrict__ meta) {
  const int kpl = blockIdx.z;
  const int* counts = meta;
  const int* offs = meta + 16;
  const int* TO = meta + 48 + kpl * 9;
  const int bx = blockIdx.x;
  const int mt = (bx & 7) * 9 + (bx >> 3);   // T1 XCD-chunk remap
  if (mt >= TO[8]) return;
  int e = 0;
#pragma unroll
  for (int q = 1; q < 8; q++) if (mt >= TO[q]) e = q;
  const int seg_start = offs[kpl * 8 + e];
  const int seg_n = counts[kpl * 8 + e];
  const int m0 = seg_start + (mt - TO[e]) * BM;
  const int rows_valid = min(BM, seg_start + seg_n - m0);
  const int nb = blockIdx.y * BN;
  const int tid = threadIdx.x, wid = tid >> 6, lane = tid & 63;
  const int wm = wid >> 1, wn = wid & 1;
  const int lane15 = lane & 15, lq = lane >> 4;

  __shared__ __align__(16) char lds[49152];  // A:0  B1:16K  Bg:32K

  const int l8 = lane >> 3, ch = lane & 7;
  long a_byte[4], b_byte[4];
#pragma unroll
  for (int i = 0; i < 4; i++) {
    const int r = wid * 32 + i * 8 + l8;
    const int rr = min(r, rows_valid - 1);
    const int tok = slot_token[kpl * N_TOK + m0 + rr];
    const int chs = ch ^ (r & 7);
    a_byte[i] = ((long)tok * CD + chs * 8) * 2;
    b_byte[i] = ((long)(e * ID + nb + r) * CD + chs * 8) * 2;
  }
  f32x4 acc_h[4][4], acc_g[4][4];
#pragma unroll
  for (int mi = 0; mi < 4; mi++)
#pragma unroll
    for (int ni = 0; ni < 4; ni++) { acc_h[mi][ni] = 0.f; acc_g[mi][ni] = 0.f; }

  for (int kb = 0; kb < CD; kb += BK) {
#pragma unroll
    for (int i = 0; i < 4; i++) {
      __builtin_amdgcn_global_load_lds(
          (const AS1 void*)((const char*)xb + a_byte[i]),
          (AS3 void*)(lds + (wid * 32 + i * 8) * 128), 16, 0, 0);
      a_byte[i] += 128;
    }
#pragma unroll
    for (int i = 0; i < 4; i++) {
      __builtin_amdgcn_global_load_lds(
          (const AS1 void*)((const char*)w1b + b_byte[i]),
          (AS3 void*)(lds + 16384 + (wid * 32 + i * 8) * 128), 16, 0, 0);
      __builtin_amdgcn_global_load_lds(
          (const AS1 void*)((const char*)wgb + b_byte[i]),
          (AS3 void*)(lds + 32768 + (wid * 32 + i * 8) * 128), 16, 0, 0);
      b_byte[i] += 128;
    }
    __syncthreads();
#pragma unroll
    for (int ks = 0; ks < 2; ks++) {
      bf16x8 af[4], bf1[4], bfg[4];
#pragma unroll
      for (int mi = 0; mi < 4; mi++) {
        const int row = wm * 64 + mi * 16 + lane15;
        const int byt = row * 128 + ((ks * 64 + lq * 16) ^ ((row & 7) << 4));
        af[mi] = *(const bf16x8*)(lds + byt);
      }
#pragma unroll
      for (int ni = 0; ni < 4; ni++) {
        const int row = wn * 64 + ni * 16 + lane15;
        const int byt = row * 128 + ((ks * 64 + lq * 16) ^ ((row & 7) << 4));
        bf1[ni] = *(const bf16x8*)(lds + 16384 + byt);
        bfg[ni] = *(const bf16x8*)(lds + 32768 + byt);
      }
#pragma unroll
      for (int mi = 0; mi < 4; mi++)
#pragma unroll
        for (int ni = 0; ni < 4; ni++) {
          acc_h[mi][ni] = __builtin_amdgcn_mfma_f32_16x16x32_bf16(af[mi], bf1[ni], acc_h[mi][ni], 0, 0, 0);
          acc_g[mi][ni] = __builtin_amdgcn_mfma_f32_16x16x32_bf16(af[mi], bfg[ni], acc_g[mi][ni], 0, 0, 0);
        }
    }
    __syncthreads();
  }

  // epilogue: silu(h)*g -> bf16, repack through LDS for coalesced store
  unsigned short* rp = (unsigned short*)lds;
#pragma unroll
  for (int mi = 0; mi < 4; mi++) {
#pragma unroll
    for (int ni = 0; ni < 4; ni++) {
      const int colLoc = wn * 64 + ni * 16 + lane15;
      const float bb1 = b1[e * ID + nb + colLoc];
      const float bbg = bg[e * ID + nb + colLoc];
#pragma unroll
      for (int j = 0; j < 4; j++) {
        const int row = wm * 64 + mi * 16 + lq * 4 + j;
        const float h = acc_h[mi][ni][j] + bb1;
        const float g = acc_g[mi][ni][j] + bbg;
        const float sv = h / (1.f + __expf(-h));
        rp[row * 128 + colLoc] = f2bf(sv * g);
      }
    }
  }
  __syncthreads();
  const long base = ((long)(kpl * N_TOK + m0)) * ID + nb;
#pragma unroll
  for (int it = 0; it < 8; it++) {
    const int chunk = it * 256 + tid;
    const int row = chunk >> 4;
    const int cc = (chunk & 15) * 8;
    if (row < rows_valid)
      *(uint4*)(act + base + (long)row * ID + cc) = *(const uint4*)(rp + row * 128 + cc);
  }
}

// ------- phase 2: dual-N merged planes, PLAIN STORES (r9 lesson: atomics
// cost ~65us). k=0 blocks own out exclusively (one expert segment per token
// per plane); k=1 blocks write partial p1; moe_add does out += p1. Numerically
// identical to the r7 two-launch =/+= order. 576 blocks >= 2/CU (r8 lesson).
__global__ __launch_bounds__(256, 2) void moe_phase2(
    const unsigned short* __restrict__ act, const unsigned short* __restrict__ w2b,
    const float* __restrict__ b2, const int* __restrict__ slot_token,
    const float* __restrict__ slot_w, float* __restrict__ out,
    float* __restrict__ p1, const int* __restrict__ meta) {
  const int kpl = blockIdx.z;
  const int* counts = meta;
  const int* offs = meta + 16;
  const int* TO = meta + 48 + kpl * 9;
  const int bx = blockIdx.x;
  const int mt = (bx & 7) * 9 + (bx >> 3);   // T1 XCD-chunk remap
  if (mt >= TO[8]) return;
  int e = 0;
#pragma unroll
  for (int q = 1; q < 8; q++) if (mt >= TO[q]) e = q;
  const int seg_start = offs[kpl * 8 + e];
  const int seg_n = counts[kpl * 8 + e];
  const int m0 = seg_start + (mt - TO[e]) * BM;
  const int rows_valid = min(BM, seg_start + seg_n - m0);
  const int nb = blockIdx.y * 256;           // dual-N: 256 output cols/block
  const int tid = threadIdx.x, wid = tid >> 6, lane = tid & 63;
  const int wm = wid >> 1, wn = wid & 1;
  const int lane15 = lane & 15, lq = lane >> 4;

  __shared__ __align__(16) char lds[49152];  // A:0  B0:16K  B1:32K

  const int l8 = lane >> 3, ch = lane & 7;
  long a_byte[4], b_byte[4];
#pragma unroll
  for (int i = 0; i < 4; i++) {
    const int r = wid * 32 + i * 8 + l8;
    const int rr = min(r, rows_valid - 1);
    const int chs = ch ^ (r & 7);
    a_byte[i] = ((long)(kpl * N_TOK + m0 + rr) * ID + chs * 8) * 2;
    b_byte[i] = ((long)(e * CD + nb + r) * ID + chs * 8) * 2;
  }
  f32x4 acc_h[4][4], acc_g[4][4];   // h: cols nb.., g: cols nb+128..
#pragma unroll
  for (int mi = 0; mi < 4; mi++)
#pragma unroll
    for (int ni = 0; ni < 4; ni++) { acc_h[mi][ni] = 0.f; acc_g[mi][ni] = 0.f; }

  for (int kb = 0; kb < ID; kb += BK) {
#pragma unroll
    for (int i = 0; i < 4; i++) {
      __builtin_amdgcn_global_load_lds(
          (const AS1 void*)((const char*)act + a_byte[i]),
          (AS3 void*)(lds + (wid * 32 + i * 8) * 128), 16, 0, 0);
      a_byte[i] += 128;
    }
#pragma unroll
    for (int i = 0; i < 4; i++) {
      __builtin_amdgcn_global_load_lds(
          (const AS1 void*)((const char*)w2b + b_byte[i]),
          (AS3 void*)(lds + 16384 + (wid * 32 + i * 8) * 128), 16, 0, 0);
      __builtin_amdgcn_global_load_lds(
          (const AS1 void*)((const char*)w2b + b_byte[i] + 262144LL),  // +128 rows
          (AS3 void*)(lds + 32768 + (wid * 32 + i * 8) * 128), 16, 0, 0);
      b_byte[i] += 128;
    }
    __syncthreads();
#pragma unroll
    for (int ks = 0; ks < 2; ks++) {
      bf16x8 af[4], bf0[4], bf1[4];
#pragma unroll
      for (int mi = 0; mi < 4; mi++) {
        const int row = wm * 64 + mi * 16 + lane15;
        const int byt = row * 128 + ((ks * 64 + lq * 16) ^ ((row & 7) << 4));
        af[mi] = *(const bf16x8*)(lds + byt);
      }
#pragma unroll
      for (int ni = 0; ni < 4; ni++) {
        const int row = wn * 64 + ni * 16 + lane15;
        const int byt = row * 128 + ((ks * 64 + lq * 16) ^ ((row & 7) << 4));
        bf0[ni] = *(const bf16x8*)(lds + 16384 + byt);
        bf1[ni] = *(const bf16x8*)(lds + 32768 + byt);
      }
#pragma unroll
      for (int mi = 0; mi < 4; mi++)
#pragma unroll
        for (int ni = 0; ni < 4; ni++) {
          acc_h[mi][ni] = __builtin_amdgcn_mfma_f32_16x16x32_bf16(af[mi], bf0[ni], acc_h[mi][ni], 0, 0, 0);
          acc_g[mi][ni] = __builtin_amdgcn_mfma_f32_16x16x32_bf16(af[mi], bf1[ni], acc_g[mi][ni], 0, 0, 0);
        }
    }
    __syncthreads();
  }

  float* dst = (kpl == 0) ? out : p1;   // wave-uniform select, no divergence
#pragma unroll
  for (int mi = 0; mi < 4; mi++) {
    int t4[4]; float w4[4]; int rv[4];
#pragma unroll
    for (int j = 0; j < 4; j++) {
      const int r = wm * 64 + mi * 16 + lq * 4 + j;
      rv[j] = (r < rows_valid);
      const int p = kpl * N_TOK + m0 + min(r, rows_valid - 1);
      t4[j] = slot_token[p];
      w4[j] = slot_w[p];
    }
#pragma unroll
    for (int half = 0; half < 2; half++) {
#pragma unroll
      for (int ni = 0; ni < 4; ni++) {
        const int col = nb + half * 128 + wn * 64 + ni * 16 + lane15;
        const float bb = b2[e * CD + col];
#pragma unroll
        for (int j = 0; j < 4; j++) {
          if (rv[j]) {
            const long o = (long)t4[j] * CD + col;
            const float a = half ? acc_g[mi][ni][j] : acc_h[mi][ni][j];
            dst[o] = (a + bb) * w4[j];
          }
        }
      }
    }
  }
}

// ---------------- out += p1 (streaming, float4) ----------------
__global__ __launch_bounds__(256) void moe_add(float* __restrict__ out,
                                               const float* __restrict__ p1) {
  const long i = ((long)blockIdx.x * 256 + threadIdx.x) * 4;
  float4 a = *(float4*)(out + i);
  const float4 b = *(const float4*)(p1 + i);
  a.x += b.x; a.y += b.y; a.z += b.z; a.w += b.w;
  *(float4*)(out + i) = a;
}

extern "C" void kernel_launch(void* const* d_in, const int* in_sizes, int n_in,
                              void* d_out, int out_size, void* d_ws, size_t ws_size,
                              hipStream_t stream) {
  const float* x  = (const float*)d_in[0];
  const float* Wr = (const float*)d_in[1];
  const float* br = (const float*)d_in[2];
  const float* W1 = (const float*)d_in[3];
  const float* b1 = (const float*)d_in[4];
  const float* Wg = (const float*)d_in[5];
  const float* bg = (const float*)d_in[6];
  const float* W2 = (const float*)d_in[7];
  const float* b2 = (const float*)d_in[8];
  float* out = (float*)d_out;
  char* ws = (char*)d_ws;

  unsigned short* xb  = (unsigned short*)(ws + XB_OFF);
  unsigned short* w1b = (unsigned short*)(ws + W1B_OFF);
  unsigned short* wgb = (unsigned short*)(ws + WGB_OFF);
  unsigned short* w2b = (unsigned short*)(ws + W2B_OFF);
  unsigned short* act = (unsigned short*)(ws + ACT_OFF);
  float* p1 = (float*)(ws + XB_OFF);   // reuse xb+w1b (dead after phase1): 33.55MB
  int*   slot_token = (int*)(ws + ST_OFF);
  float* slot_w     = (float*)(ws + SW_OFF);
  int*   tok_e      = (int*)(ws + TE_OFF);
  float* tok_w      = (float*)(ws + TW_OFF);
  int*   meta       = (int*)(ws + META_OFF);

  moe_router_cvt<<<N_TOK / 4, 256, 0, stream>>>(x, Wr, br, xb, tok_e, tok_w);
  moe_sort<<<1, 256, 0, stream>>>(tok_e, tok_w, meta, slot_token, slot_w);
  moe_tw<<<dim3(16, 16, 24), 256, 0, stream>>>(W1, Wg, W2, w1b, wgb, w2b);
  moe_phase1<<<dim3(MAXMT, ID / BN, 2), 256, 0, stream>>>(xb, w1b, wgb, b1, bg, act, slot_token, meta);
  moe_phase2<<<dim3(MAXMT, CD / 256, 2), 256, 0, stream>>>(act, w2b, b2, slot_token, slot_w, out, p1, meta);
  moe_add<<<(N_TOK * CD) / (256 * 4), 256, 0, stream>>>(out, p1);
}